// Round 3
// baseline (145.561 us; speedup 1.0000x reference)
//
#include <hip/hip_runtime.h>

typedef __bf16 bf16_t;
typedef float  f32x4_t  __attribute__((ext_vector_type(4)));
typedef bf16_t bf16x4_t __attribute__((ext_vector_type(4)));
typedef bf16_t bf16x8_t __attribute__((ext_vector_type(8)));

#define BATCH  4
#define S_LEN  4096
#define DMODEL 1024
#define HDIM   64
#define NQT    (S_LEN / 16)   // 256 q-tiles per batch

// ---------------------------------------------------------------------------
// Kernel 0: transpose+cast W -> Wt[192][1024] bf16.
// ---------------------------------------------------------------------------
__global__ __launch_bounds__(256) void wt_kernel(
    const float* __restrict__ Wk, const float* __restrict__ Wq,
    const float* __restrict__ Wv, bf16_t* __restrict__ Wt)
{
    __shared__ bf16_t t[64][65];
    const float* W = (blockIdx.y == 0) ? Wq : (blockIdx.y == 1) ? Wk : Wv;
    const int k0 = blockIdx.x * 64;
    const int a = threadIdx.x & 63, r = threadIdx.x >> 6;
#pragma unroll
    for (int i = 0; i < 16; ++i) {
        const int k = r + i * 4;
        t[k][a] = (bf16_t)W[(long)(k0 + k) * HDIM + a];
    }
    __syncthreads();
#pragma unroll
    for (int i = 0; i < 16; ++i) {
        const int h = r + i * 4;
        Wt[((long)(blockIdx.y * 64 + h)) * DMODEL + k0 + a] = t[a][h];
    }
}

// ---------------------------------------------------------------------------
// Kernel 1: QKV projection via bf16 MFMA (fp32 accum).  Unchanged from R2.
// ---------------------------------------------------------------------------
__global__ __launch_bounds__(512) void qkv_mfma_kernel(
    const float* __restrict__ x, const bf16_t* __restrict__ Wt,
    const float* __restrict__ bk, const float* __restrict__ bq,
    const float* __restrict__ bv,
    bf16_t* __restrict__ Qb, bf16_t* __restrict__ Kb, bf16_t* __restrict__ Vt)
{
    __shared__ bf16_t xs[64 * 64];
    __shared__ bf16_t ws[192 * 64];
    __shared__ bf16_t vs[64][72];

    const int tid  = threadIdx.x;
    const int lane = tid & 63;
    const int w    = tid >> 6;
    const int g    = lane >> 4, n = lane & 15;
    const long rowbase = (long)blockIdx.x * 64;

    const int srow = tid >> 3, sseg = tid & 7;
    const int mrow = (w >> 2) * 32;
    const int ncol = (w & 3) * 48;

    f32x4_t acc[2][3];
#pragma unroll
    for (int mt = 0; mt < 2; ++mt)
#pragma unroll
        for (int nt = 0; nt < 3; ++nt) acc[mt][nt] = (f32x4_t){0.f, 0.f, 0.f, 0.f};

    for (int kc = 0; kc < 16; ++kc) {
        const int k0 = kc * 64;
        const float* xp = x + (rowbase + srow) * DMODEL + k0 + sseg * 8;
        const float4 xa = *reinterpret_cast<const float4*>(xp);
        const float4 xb = *reinterpret_cast<const float4*>(xp + 4);
        bf16x8_t wreg[3];
#pragma unroll
        for (int i = 0; i < 3; ++i) {
            const int s = tid + i * 512;
            wreg[i] = *reinterpret_cast<const bf16x8_t*>(
                Wt + ((long)(s >> 3)) * DMODEL + k0 + (s & 7) * 8);
        }
        bf16x8_t xv;
        xv[0] = (bf16_t)xa.x; xv[1] = (bf16_t)xa.y;
        xv[2] = (bf16_t)xa.z; xv[3] = (bf16_t)xa.w;
        xv[4] = (bf16_t)xb.x; xv[5] = (bf16_t)xb.y;
        xv[6] = (bf16_t)xb.z; xv[7] = (bf16_t)xb.w;

        __syncthreads();
        *reinterpret_cast<bf16x8_t*>(
            (char*)xs + srow * 128 + ((sseg ^ (srow & 7)) * 16)) = xv;
#pragma unroll
        for (int i = 0; i < 3; ++i) {
            const int s = tid + i * 512;
            const int wrow = s >> 3, wseg = s & 7;
            *reinterpret_cast<bf16x8_t*>(
                (char*)ws + wrow * 128 + ((wseg ^ (wrow & 7)) * 16)) = wreg[i];
        }
        __syncthreads();

#pragma unroll
        for (int ks = 0; ks < 2; ++ks) {
            const int sb = ks * 4;
            bf16x8_t afr[2], bfr[3];
#pragma unroll
            for (int mt = 0; mt < 2; ++mt) {
                const int row = mrow + mt * 16 + n;
                afr[mt] = *reinterpret_cast<const bf16x8_t*>(
                    (char*)xs + row * 128 + (((sb + g) ^ (row & 7)) * 16));
            }
#pragma unroll
            for (int nt = 0; nt < 3; ++nt) {
                const int row = ncol + nt * 16 + n;
                bfr[nt] = *reinterpret_cast<const bf16x8_t*>(
                    (char*)ws + row * 128 + (((sb + g) ^ (row & 7)) * 16));
            }
#pragma unroll
            for (int mt = 0; mt < 2; ++mt)
#pragma unroll
                for (int nt = 0; nt < 3; ++nt)
                    acc[mt][nt] = __builtin_amdgcn_mfma_f32_16x16x32_bf16(
                        afr[mt], bfr[nt], acc[mt][nt], 0, 0, 0);
        }
    }

#pragma unroll
    for (int nt = 0; nt < 3; ++nt) {
        const int c = ncol + nt * 16 + n;
        float bias;
        if (c < 64)       bias = bq[c];
        else if (c < 128) bias = bk[c - 64];
        else              bias = bv[c - 128];
#pragma unroll
        for (int mt = 0; mt < 2; ++mt) {
#pragma unroll
            for (int r = 0; r < 4; ++r) {
                const int row = mrow + mt * 16 + 4 * g + r;
                const float val = acc[mt][nt][r] + bias;
                if (c < 64)
                    Qb[(rowbase + row) * HDIM + c] = (bf16_t)(val * 0.125f);
                else if (c < 128)
                    Kb[(rowbase + row) * HDIM + (c - 64)] = (bf16_t)val;
                else
                    vs[c - 128][row] = (bf16_t)val;
            }
        }
    }
    __syncthreads();
    {
        const int h = tid >> 3, sj = (tid & 7) * 8;
        const int bb = (int)(rowbase >> 12);
        const int s0 = (int)(rowbase & (S_LEN - 1));
        const bf16x8_t vv = *reinterpret_cast<const bf16x8_t*>(&vs[h][sj]);
        *reinterpret_cast<bf16x8_t*>(
            Vt + ((long)(bb * 64 + h)) * S_LEN + s0 + sj) = vv;
    }
}

// ---------------------------------------------------------------------------
// Kernel 2: causal flash attention, split-K x4, swapped QK^T.
// Wave w of 4 handles key-blocks j = w (mod 4) of 64 keys for one 16-q tile.
//   S^T = mfma(K_frag, Q_frag): lane (g,n) holds S[key=k0+16f+4g+r][q=q0+n]
//   -> softmax over keys is lane-local (16 vals) + 2 shfl_xor (g-groups).
//   P bounced through per-wave XOR-swizzled LDS [16 q][64 key] bf16 into
//   PV A-frags (no fences: same-wave DS ops are HW in-order, compiler
//   preserves order via may-alias).  T13 defer-max (THR=8) skips O-rescale.
// ---------------------------------------------------------------------------
__global__ __launch_bounds__(256) void attn_kernel(
    const bf16_t* __restrict__ Qb, const bf16_t* __restrict__ Kb,
    const bf16_t* __restrict__ Vt, float* __restrict__ out)
{
    __shared__ bf16_t plds[4][16 * 64];   // per-wave, XOR-swizzled, 2 KB each
    __shared__ float  olds[4][16][64];
    __shared__ float  mlds[4][16];
    __shared__ float  llds[4][16];

    const int tid  = threadIdx.x;
    const int w    = tid >> 6;
    const int lane = tid & 63;
    const int g    = lane >> 4, n = lane & 15;
    const int b    = blockIdx.y;
    const int bx   = blockIdx.x;
    const int tile = (bx & 1) ? (NQT - 1 - (bx >> 1)) : (bx >> 1);
    const int q0   = tile * 16;
    const long bS  = (long)b * S_LEN;

    char* const pb  = (char*)plds[w];
    const int  swz  = (n & 7) << 4;
    const f32x4_t zero = {0.f, 0.f, 0.f, 0.f};

    // Q B-frags: Q[q0+n][g*8+{0..7}] and +32 (pre-scaled by 1/8)
    const bf16_t* qbase = &Qb[(bS + q0 + n) * HDIM + g * 8];
    const bf16x8_t bq0 = *reinterpret_cast<const bf16x8_t*>(qbase);
    const bf16x8_t bq1 = *reinterpret_cast<const bf16x8_t*>(qbase + 32);

    f32x4_t o[4];   // o[nt][r] = O[q=q0+4g+r][h=16nt+n]
#pragma unroll
    for (int nt = 0; nt < 4; ++nt) o[nt] = zero;
    float m_run = -1e30f;   // column max (q=q0+n), replicated across g
    float l_par = 0.f;      // per-lane partial denominator

    const int nkb = (q0 >> 6) + 1;   // 64-key blocks needed (causal)
    for (int j = w; j < nkb; j += 4) {
        const int k0 = j * 64;

        // ---- QK^T (swapped): A = K rows, B = Q rows
        const bf16_t* kbase = &Kb[(bS + k0 + n) * HDIM + g * 8];
        f32x4_t s[4];
#pragma unroll
        for (int f = 0; f < 4; ++f) {
            const bf16x8_t ka0 = *reinterpret_cast<const bf16x8_t*>(kbase + f * 16 * HDIM);
            const bf16x8_t ka1 = *reinterpret_cast<const bf16x8_t*>(kbase + f * 16 * HDIM + 32);
            s[f] = __builtin_amdgcn_mfma_f32_16x16x32_bf16(ka0, bq0, zero, 0, 0, 0);
            s[f] = __builtin_amdgcn_mfma_f32_16x16x32_bf16(ka1, bq1, s[f], 0, 0, 0);
        }

        // ---- causal mask: key = k0+16f+4g+r vs q = q0+n
        const int q = q0 + n;
#pragma unroll
        for (int f = 0; f < 4; ++f)
#pragma unroll
            for (int r = 0; r < 4; ++r)
                if (k0 + 16 * f + 4 * g + r > q) s[f][r] = -1e30f;

        // ---- column max: 15 local max + 2 shfls
        float fm0 = fmaxf(fmaxf(s[0][0], s[0][1]), fmaxf(s[0][2], s[0][3]));
        float fm1 = fmaxf(fmaxf(s[1][0], s[1][1]), fmaxf(s[1][2], s[1][3]));
        float fm2 = fmaxf(fmaxf(s[2][0], s[2][1]), fmaxf(s[2][2], s[2][3]));
        float fm3 = fmaxf(fmaxf(s[3][0], s[3][1]), fmaxf(s[3][2], s[3][3]));
        float pm = fmaxf(fmaxf(fm0, fm1), fmaxf(fm2, fm3));
        pm = fmaxf(pm, __shfl_xor(pm, 16));
        pm = fmaxf(pm, __shfl_xor(pm, 32));

        // ---- T13 defer-max: rescale only when max grows by > 8
        if (__any(pm > m_run + 8.f)) {
            const float mn    = fmaxf(m_run, pm);
            const float alpha = __expf(m_run - mn);
            m_run = mn;
            l_par *= alpha;
#pragma unroll
            for (int r = 0; r < 4; ++r) {
                const float ar = __shfl(alpha, 4 * g + r);
#pragma unroll
                for (int nt = 0; nt < 4; ++nt) o[nt][r] *= ar;
            }
        }

        // ---- P = exp(s - m), lane-local; pack 4 bf16 -> swizzled LDS
#pragma unroll
        for (int f = 0; f < 4; ++f) {
            bf16x4_t pk;
#pragma unroll
            for (int r = 0; r < 4; ++r) {
                const float p = __expf(s[f][r] - m_run);
                l_par += p;
                pk[r] = (bf16_t)p;
            }
            *reinterpret_cast<bf16x4_t*>(pb + n * 128 + ((32 * f + 8 * g) ^ swz)) = pk;
        }

        // ---- PV: A = P rows from LDS (HW in-order DS, no fence needed)
#pragma unroll
        for (int ks = 0; ks < 2; ++ks) {
            const bf16x8_t pa = *reinterpret_cast<const bf16x8_t*>(
                pb + n * 128 + ((64 * ks + 16 * g) ^ swz));
            const bf16_t* vbase = &Vt[((long)(b * 64 + n)) * S_LEN + k0 + ks * 32 + g * 8];
#pragma unroll
            for (int nt = 0; nt < 4; ++nt) {
                const bf16x8_t vb = *reinterpret_cast<const bf16x8_t*>(vbase + nt * 16 * S_LEN);
                o[nt] = __builtin_amdgcn_mfma_f32_16x16x32_bf16(pa, vb, o[nt], 0, 0, 0);
            }
        }
    }

    // ---- finish l: reduce partial sums across g-lanes
    float l_run = l_par;
    l_run += __shfl_xor(l_run, 16);
    l_run += __shfl_xor(l_run, 32);

    // ---- publish per-wave partial state
    if (g == 0) { mlds[w][n] = m_run; llds[w][n] = l_run; }
#pragma unroll
    for (int nt = 0; nt < 4; ++nt)
#pragma unroll
        for (int r = 0; r < 4; ++r)
            olds[w][4 * g + r][nt * 16 + n] = o[nt][r];
    __syncthreads();

    // ---- merge 4 split-K partials, write fp32 out
    {
        const int c  = tid & 63;
        const int rg = tid >> 6;
#pragma unroll
        for (int i = 0; i < 4; ++i) {
            const int row = rg * 4 + i;
            const float m0 = mlds[0][row], m1 = mlds[1][row];
            const float m2 = mlds[2][row], m3 = mlds[3][row];
            const float mm = fmaxf(fmaxf(m0, m1), fmaxf(m2, m3));
            const float a0 = __expf(m0 - mm), a1 = __expf(m1 - mm);
            const float a2 = __expf(m2 - mm), a3 = __expf(m3 - mm);
            const float den = llds[0][row] * a0 + llds[1][row] * a1 +
                              llds[2][row] * a2 + llds[3][row] * a3;
            const float num = olds[0][row][c] * a0 + olds[1][row][c] * a1 +
                              olds[2][row][c] * a2 + olds[3][row][c] * a3;
            out[(bS + q0 + row) * HDIM + c] = num / den;
        }
    }
}

// ---------------------------------------------------------------------------
extern "C" void kernel_launch(void* const* d_in, const int* in_sizes, int n_in,
                              void* d_out, int out_size, void* d_ws, size_t ws_size,
                              hipStream_t stream)
{
    const float* x  = (const float*)d_in[0];
    const float* Wk = (const float*)d_in[1];
    const float* bk = (const float*)d_in[2];
    const float* Wq = (const float*)d_in[3];
    const float* bq = (const float*)d_in[4];
    const float* Wv = (const float*)d_in[5];
    const float* bv = (const float*)d_in[6];
    float* out = (float*)d_out;

    const size_t elems = (size_t)BATCH * S_LEN * HDIM;  // 1,048,576
    bf16_t* Qb = (bf16_t*)d_ws;
    bf16_t* Kb = Qb + elems;
    bf16_t* Vt = Kb + elems;
    bf16_t* Wt = Vt + elems;   // 192*1024 bf16

    wt_kernel<<<dim3(DMODEL / 64, 3), 256, 0, stream>>>(Wk, Wq, Wv, Wt);
    qkv_mfma_kernel<<<256, 512, 0, stream>>>(x, Wt, bk, bq, bv, Qb, Kb, Vt);
    attn_kernel<<<dim3(NQT, BATCH), 256, 0, stream>>>(Qb, Kb, Vt, out);
}

// Round 4
// 96.473 us; speedup vs baseline: 1.5088x; 1.5088x over previous
//
#include <hip/hip_runtime.h>

typedef __bf16 bf16_t;
typedef float  f32x4_t  __attribute__((ext_vector_type(4)));
typedef bf16_t bf16x4_t __attribute__((ext_vector_type(4)));
typedef bf16_t bf16x8_t __attribute__((ext_vector_type(8)));

#define BATCH  4
#define S_LEN  4096
#define DMODEL 1024
#define HDIM   64
#define NQT    (S_LEN / 16)   // 256 q-tiles per batch

// ---------------------------------------------------------------------------
// Kernel 0: transpose+cast W -> Wt[192][1024] bf16.
// ---------------------------------------------------------------------------
__global__ __launch_bounds__(256) void wt_kernel(
    const float* __restrict__ Wk, const float* __restrict__ Wq,
    const float* __restrict__ Wv, bf16_t* __restrict__ Wt)
{
    __shared__ bf16_t t[64][65];
    const float* W = (blockIdx.y == 0) ? Wq : (blockIdx.y == 1) ? Wk : Wv;
    const int k0 = blockIdx.x * 64;
    const int a = threadIdx.x & 63, r = threadIdx.x >> 6;
#pragma unroll
    for (int i = 0; i < 16; ++i) {
        const int k = r + i * 4;
        t[k][a] = (bf16_t)W[(long)(k0 + k) * HDIM + a];
    }
    __syncthreads();
#pragma unroll
    for (int i = 0; i < 16; ++i) {
        const int h = r + i * 4;
        Wt[((long)(blockIdx.y * 64 + h)) * DMODEL + k0 + a] = t[a][h];
    }
}

// ---------------------------------------------------------------------------
// Kernel 1: QKV projection via bf16 MFMA (fp32 accum).  Unchanged from R3.
// ---------------------------------------------------------------------------
__global__ __launch_bounds__(512) void qkv_mfma_kernel(
    const float* __restrict__ x, const bf16_t* __restrict__ Wt,
    const float* __restrict__ bk, const float* __restrict__ bq,
    const float* __restrict__ bv,
    bf16_t* __restrict__ Qb, bf16_t* __restrict__ Kb, bf16_t* __restrict__ Vt)
{
    __shared__ bf16_t xs[64 * 64];
    __shared__ bf16_t ws[192 * 64];
    __shared__ bf16_t vs[64][72];

    const int tid  = threadIdx.x;
    const int lane = tid & 63;
    const int w    = tid >> 6;
    const int g    = lane >> 4, n = lane & 15;
    const long rowbase = (long)blockIdx.x * 64;

    const int srow = tid >> 3, sseg = tid & 7;
    const int mrow = (w >> 2) * 32;
    const int ncol = (w & 3) * 48;

    f32x4_t acc[2][3];
#pragma unroll
    for (int mt = 0; mt < 2; ++mt)
#pragma unroll
        for (int nt = 0; nt < 3; ++nt) acc[mt][nt] = (f32x4_t){0.f, 0.f, 0.f, 0.f};

    for (int kc = 0; kc < 16; ++kc) {
        const int k0 = kc * 64;
        const float* xp = x + (rowbase + srow) * DMODEL + k0 + sseg * 8;
        const float4 xa = *reinterpret_cast<const float4*>(xp);
        const float4 xb = *reinterpret_cast<const float4*>(xp + 4);
        bf16x8_t wreg[3];
#pragma unroll
        for (int i = 0; i < 3; ++i) {
            const int s = tid + i * 512;
            wreg[i] = *reinterpret_cast<const bf16x8_t*>(
                Wt + ((long)(s >> 3)) * DMODEL + k0 + (s & 7) * 8);
        }
        bf16x8_t xv;
        xv[0] = (bf16_t)xa.x; xv[1] = (bf16_t)xa.y;
        xv[2] = (bf16_t)xa.z; xv[3] = (bf16_t)xa.w;
        xv[4] = (bf16_t)xb.x; xv[5] = (bf16_t)xb.y;
        xv[6] = (bf16_t)xb.z; xv[7] = (bf16_t)xb.w;

        __syncthreads();
        *reinterpret_cast<bf16x8_t*>(
            (char*)xs + srow * 128 + ((sseg ^ (srow & 7)) * 16)) = xv;
#pragma unroll
        for (int i = 0; i < 3; ++i) {
            const int s = tid + i * 512;
            const int wrow = s >> 3, wseg = s & 7;
            *reinterpret_cast<bf16x8_t*>(
                (char*)ws + wrow * 128 + ((wseg ^ (wrow & 7)) * 16)) = wreg[i];
        }
        __syncthreads();

#pragma unroll
        for (int ks = 0; ks < 2; ++ks) {
            const int sb = ks * 4;
            bf16x8_t afr[2], bfr[3];
#pragma unroll
            for (int mt = 0; mt < 2; ++mt) {
                const int row = mrow + mt * 16 + n;
                afr[mt] = *reinterpret_cast<const bf16x8_t*>(
                    (char*)xs + row * 128 + (((sb + g) ^ (row & 7)) * 16));
            }
#pragma unroll
            for (int nt = 0; nt < 3; ++nt) {
                const int row = ncol + nt * 16 + n;
                bfr[nt] = *reinterpret_cast<const bf16x8_t*>(
                    (char*)ws + row * 128 + (((sb + g) ^ (row & 7)) * 16));
            }
#pragma unroll
            for (int mt = 0; mt < 2; ++mt)
#pragma unroll
                for (int nt = 0; nt < 3; ++nt)
                    acc[mt][nt] = __builtin_amdgcn_mfma_f32_16x16x32_bf16(
                        afr[mt], bfr[nt], acc[mt][nt], 0, 0, 0);
        }
    }

#pragma unroll
    for (int nt = 0; nt < 3; ++nt) {
        const int c = ncol + nt * 16 + n;
        float bias;
        if (c < 64)       bias = bq[c];
        else if (c < 128) bias = bk[c - 64];
        else              bias = bv[c - 128];
#pragma unroll
        for (int mt = 0; mt < 2; ++mt) {
#pragma unroll
            for (int r = 0; r < 4; ++r) {
                const int row = mrow + mt * 16 + 4 * g + r;
                const float val = acc[mt][nt][r] + bias;
                if (c < 64)
                    Qb[(rowbase + row) * HDIM + c] = (bf16_t)(val * 0.125f);
                else if (c < 128)
                    Kb[(rowbase + row) * HDIM + (c - 64)] = (bf16_t)val;
                else
                    vs[c - 128][row] = (bf16_t)val;
            }
        }
    }
    __syncthreads();
    {
        const int h = tid >> 3, sj = (tid & 7) * 8;
        const int bb = (int)(rowbase >> 12);
        const int s0 = (int)(rowbase & (S_LEN - 1));
        const bf16x8_t vv = *reinterpret_cast<const bf16x8_t*>(&vs[h][sj]);
        *reinterpret_cast<bf16x8_t*>(
            Vt + ((long)(bb * 64 + h)) * S_LEN + s0 + sj) = vv;
    }
}

// ---------------------------------------------------------------------------
// Kernel 2: causal flash attention, split-K x4, swapped QK^T, balanced pairs.
// Block = pair of q-tiles (p, NQT-1-p) -> every block ~66 key-blocks of work
// (uniform; no tail).  Ping-pong register prefetch of next K AND V tiles
// hides L2 latency under the current iteration's MFMA+softmax.  Causal mask
// applied only on the last (diagonal) key-block.  T13 defer-max; T5 setprio.
// ---------------------------------------------------------------------------
__global__ __launch_bounds__(256) void attn_kernel(
    const bf16_t* __restrict__ Qb, const bf16_t* __restrict__ Kb,
    const bf16_t* __restrict__ Vt, float* __restrict__ out)
{
    __shared__ bf16_t plds[4][2][16 * 64];   // per-wave dbuf P, 16 KB
    __shared__ float  olds[4][16][64];       // 16 KB
    __shared__ float  mlds[4][16];
    __shared__ float  llds[4][16];

    const int tid  = threadIdx.x;
    const int w    = tid >> 6;
    const int lane = tid & 63;
    const int g    = lane >> 4, n = lane & 15;
    const int b    = blockIdx.y;
    const long bS  = (long)b * S_LEN;
    const long bV  = (long)b * 64;
    const int  swz = (n & 7) << 4;
    const f32x4_t zero = {0.f, 0.f, 0.f, 0.f};

#pragma unroll 1
    for (int half = 0; half < 2; ++half) {
        const int tile = half ? (NQT - 1 - blockIdx.x) : blockIdx.x;
        const int q0   = tile * 16;
        const int nkb  = (q0 >> 6) + 1;   // 64-key blocks (causal)

        // Q B-frags (pre-scaled by 1/8)
        const bf16_t* qbase = &Qb[(bS + q0 + n) * HDIM + g * 8];
        const bf16x8_t bq0 = *reinterpret_cast<const bf16x8_t*>(qbase);
        const bf16x8_t bq1 = *reinterpret_cast<const bf16x8_t*>(qbase + 32);

        f32x4_t o[4];
#pragma unroll
        for (int nt = 0; nt < 4; ++nt) o[nt] = zero;
        float m_run = -1e30f;   // running max for query q0+n (replicated over g)
        float l_par = 0.f;      // per-lane partial denominator

        bf16x8_t kA[8], vA[8], kB[8], vB[8];

        auto LOAD = [&](bf16x8_t* kr, bf16x8_t* vr, int j) {
            const int k0 = j * 64;
            const bf16_t* kb = &Kb[(bS + k0 + n) * HDIM + g * 8];
#pragma unroll
            for (int f = 0; f < 4; ++f) {
                kr[2 * f]     = *reinterpret_cast<const bf16x8_t*>(kb + f * 16 * HDIM);
                kr[2 * f + 1] = *reinterpret_cast<const bf16x8_t*>(kb + f * 16 * HDIM + 32);
            }
            const bf16_t* vb = &Vt[(bV + n) * S_LEN + k0 + g * 8];
#pragma unroll
            for (int ks = 0; ks < 2; ++ks)
#pragma unroll
                for (int nt = 0; nt < 4; ++nt)
                    vr[ks * 4 + nt] = *reinterpret_cast<const bf16x8_t*>(
                        vb + (long)(nt * 16) * S_LEN + ks * 32);
        };

        auto COMPUTE = [&](const bf16x8_t* kr, const bf16x8_t* vr, int j) {
            const int k0 = j * 64;
            f32x4_t s[4];
            __builtin_amdgcn_s_setprio(1);
#pragma unroll
            for (int f = 0; f < 4; ++f) {
                s[f] = __builtin_amdgcn_mfma_f32_16x16x32_bf16(kr[2 * f],     bq0, zero, 0, 0, 0);
                s[f] = __builtin_amdgcn_mfma_f32_16x16x32_bf16(kr[2 * f + 1], bq1, s[f], 0, 0, 0);
            }
            __builtin_amdgcn_s_setprio(0);

            if (j == nkb - 1) {   // only the diagonal block needs masking
                const int q = q0 + n;
#pragma unroll
                for (int f = 0; f < 4; ++f)
#pragma unroll
                    for (int r = 0; r < 4; ++r)
                        if (k0 + 16 * f + 4 * g + r > q) s[f][r] = -1e30f;
            }

            // column max: 15 local + 2 shfl
            float fm0 = fmaxf(fmaxf(s[0][0], s[0][1]), fmaxf(s[0][2], s[0][3]));
            float fm1 = fmaxf(fmaxf(s[1][0], s[1][1]), fmaxf(s[1][2], s[1][3]));
            float fm2 = fmaxf(fmaxf(s[2][0], s[2][1]), fmaxf(s[2][2], s[2][3]));
            float fm3 = fmaxf(fmaxf(s[3][0], s[3][1]), fmaxf(s[3][2], s[3][3]));
            float pm = fmaxf(fmaxf(fm0, fm1), fmaxf(fm2, fm3));
            pm = fmaxf(pm, __shfl_xor(pm, 16));
            pm = fmaxf(pm, __shfl_xor(pm, 32));

            if (__any(pm > m_run + 8.f)) {   // T13 defer-max
                const float mn = fmaxf(m_run, pm);
                const float al = __expf(m_run - mn);
                m_run = mn;
                l_par *= al;
#pragma unroll
                for (int r = 0; r < 4; ++r) {
                    const float ar = __shfl(al, 4 * g + r);
#pragma unroll
                    for (int nt = 0; nt < 4; ++nt) o[nt][r] *= ar;
                }
            }

            // P = exp(s - m) -> swizzled per-wave LDS (dbuf on iteration parity)
            char* pb = (char*)plds[w][(j >> 2) & 1];
#pragma unroll
            for (int f = 0; f < 4; ++f) {
                bf16x4_t pk;
#pragma unroll
                for (int r = 0; r < 4; ++r) {
                    const float p = __expf(s[f][r] - m_run);
                    l_par += p;
                    pk[r] = (bf16_t)p;
                }
                *reinterpret_cast<bf16x4_t*>(pb + n * 128 + ((32 * f + 8 * g) ^ swz)) = pk;
            }

            // PV: A = P rows from LDS, B = V from prefetched regs
            __builtin_amdgcn_s_setprio(1);
#pragma unroll
            for (int ks = 0; ks < 2; ++ks) {
                const bf16x8_t pa = *reinterpret_cast<const bf16x8_t*>(
                    pb + n * 128 + ((64 * ks + 16 * g) ^ swz));
#pragma unroll
                for (int nt = 0; nt < 4; ++nt)
                    o[nt] = __builtin_amdgcn_mfma_f32_16x16x32_bf16(
                        pa, vr[ks * 4 + nt], o[nt], 0, 0, 0);
            }
            __builtin_amdgcn_s_setprio(0);
        };

        if (w < nkb) {
            int j = w;
            LOAD(kA, vA, j);
            for (;;) {
                int jn = j + 4;
                if (jn < nkb) LOAD(kB, vB, jn);
                COMPUTE(kA, vA, j);
                j = jn;
                if (j >= nkb) break;
                jn = j + 4;
                if (jn < nkb) LOAD(kA, vA, jn);
                COMPUTE(kB, vB, j);
                j = jn;
                if (j >= nkb) break;
            }
        }

        // finish l across g-lanes
        float l_run = l_par;
        l_run += __shfl_xor(l_run, 16);
        l_run += __shfl_xor(l_run, 32);

        // publish per-wave partials
        if (g == 0) { mlds[w][n] = m_run; llds[w][n] = l_run; }
#pragma unroll
        for (int nt = 0; nt < 4; ++nt)
#pragma unroll
            for (int r = 0; r < 4; ++r)
                olds[w][4 * g + r][nt * 16 + n] = o[nt][r];
        __syncthreads();

        // merge 4 split-K partials, write fp32 out
        {
            const int c  = tid & 63;
            const int rg = tid >> 6;
#pragma unroll
            for (int i = 0; i < 4; ++i) {
                const int row = rg * 4 + i;
                const float m0 = mlds[0][row], m1 = mlds[1][row];
                const float m2 = mlds[2][row], m3 = mlds[3][row];
                const float mm = fmaxf(fmaxf(m0, m1), fmaxf(m2, m3));
                const float a0 = __expf(m0 - mm), a1 = __expf(m1 - mm);
                const float a2 = __expf(m2 - mm), a3 = __expf(m3 - mm);
                const float den = llds[0][row] * a0 + llds[1][row] * a1 +
                                  llds[2][row] * a2 + llds[3][row] * a3;
                const float num = olds[0][row][c] * a0 + olds[1][row][c] * a1 +
                                  olds[2][row][c] * a2 + olds[3][row][c] * a3;
                out[(bS + q0 + row) * HDIM + c] = num / den;
            }
        }
        __syncthreads();   // olds/mlds/llds reused by the second half
    }
}

// ---------------------------------------------------------------------------
extern "C" void kernel_launch(void* const* d_in, const int* in_sizes, int n_in,
                              void* d_out, int out_size, void* d_ws, size_t ws_size,
                              hipStream_t stream)
{
    const float* x  = (const float*)d_in[0];
    const float* Wk = (const float*)d_in[1];
    const float* bk = (const float*)d_in[2];
    const float* Wq = (const float*)d_in[3];
    const float* bq = (const float*)d_in[4];
    const float* Wv = (const float*)d_in[5];
    const float* bv = (const float*)d_in[6];
    float* out = (float*)d_out;

    const size_t elems = (size_t)BATCH * S_LEN * HDIM;  // 1,048,576
    bf16_t* Qb = (bf16_t*)d_ws;
    bf16_t* Kb = Qb + elems;
    bf16_t* Vt = Kb + elems;
    bf16_t* Wt = Vt + elems;   // 192*1024 bf16

    wt_kernel<<<dim3(DMODEL / 64, 3), 256, 0, stream>>>(Wk, Wq, Wv, Wt);
    qkv_mfma_kernel<<<256, 512, 0, stream>>>(x, Wt, bk, bq, bv, Qb, Kb, Vt);
    attn_kernel<<<dim3(NQT / 2, BATCH), 256, 0, stream>>>(Qb, Kb, Vt, out);
}

// Round 6
// 91.035 us; speedup vs baseline: 1.5989x; 1.0597x over previous
//
#include <hip/hip_runtime.h>

typedef __bf16 bf16_t;
typedef float  f32x4_t  __attribute__((ext_vector_type(4)));
typedef bf16_t bf16x4_t __attribute__((ext_vector_type(4)));
typedef bf16_t bf16x8_t __attribute__((ext_vector_type(8)));

#define BATCH  4
#define S_LEN  4096
#define DMODEL 1024
#define HDIM   64
#define NQT    (S_LEN / 16)   // 256 q-tiles per batch

// Q pre-scale: 1/sqrt(64) * log2(e)  ->  softmax runs in exp2 domain
#define QSCALE 0.180336879f
// defer-max threshold 8 (nat) in log2 domain
#define DTHR   11.5415603f

// exp2 via the HW instruction (v_exp_f32 is base-2 on gfx950)
__device__ __forceinline__ float ex2(float x) { return __builtin_amdgcn_exp2f(x); }

// ---------------------------------------------------------------------------
// Kernel 0: transpose+cast W -> Wt[192][1024] bf16.
// ---------------------------------------------------------------------------
__global__ __launch_bounds__(256) void wt_kernel(
    const float* __restrict__ Wk, const float* __restrict__ Wq,
    const float* __restrict__ Wv, bf16_t* __restrict__ Wt)
{
    __shared__ bf16_t t[64][65];
    const float* W = (blockIdx.y == 0) ? Wq : (blockIdx.y == 1) ? Wk : Wv;
    const int k0 = blockIdx.x * 64;
    const int a = threadIdx.x & 63, r = threadIdx.x >> 6;
#pragma unroll
    for (int i = 0; i < 16; ++i) {
        const int k = r + i * 4;
        t[k][a] = (bf16_t)W[(long)(k0 + k) * HDIM + a];
    }
    __syncthreads();
#pragma unroll
    for (int i = 0; i < 16; ++i) {
        const int h = r + i * 4;
        Wt[((long)(blockIdx.y * 64 + h)) * DMODEL + k0 + a] = t[a][h];
    }
}

// ---------------------------------------------------------------------------
// Kernel 1: QKV projection via bf16 MFMA (fp32 accum).  Q scale -> QSCALE.
// ---------------------------------------------------------------------------
__global__ __launch_bounds__(512) void qkv_mfma_kernel(
    const float* __restrict__ x, const bf16_t* __restrict__ Wt,
    const float* __restrict__ bk, const float* __restrict__ bq,
    const float* __restrict__ bv,
    bf16_t* __restrict__ Qb, bf16_t* __restrict__ Kb, bf16_t* __restrict__ Vt)
{
    __shared__ bf16_t xs[64 * 64];
    __shared__ bf16_t ws[192 * 64];
    __shared__ bf16_t vs[64][72];

    const int tid  = threadIdx.x;
    const int lane = tid & 63;
    const int w    = tid >> 6;
    const int g    = lane >> 4, n = lane & 15;
    const long rowbase = (long)blockIdx.x * 64;

    const int srow = tid >> 3, sseg = tid & 7;
    const int mrow = (w >> 2) * 32;
    const int ncol = (w & 3) * 48;

    f32x4_t acc[2][3];
#pragma unroll
    for (int mt = 0; mt < 2; ++mt)
#pragma unroll
        for (int nt = 0; nt < 3; ++nt) acc[mt][nt] = (f32x4_t){0.f, 0.f, 0.f, 0.f};

    for (int kc = 0; kc < 16; ++kc) {
        const int k0 = kc * 64;
        const float* xp = x + (rowbase + srow) * DMODEL + k0 + sseg * 8;
        const float4 xa = *reinterpret_cast<const float4*>(xp);
        const float4 xb = *reinterpret_cast<const float4*>(xp + 4);
        bf16x8_t wreg[3];
#pragma unroll
        for (int i = 0; i < 3; ++i) {
            const int s = tid + i * 512;
            wreg[i] = *reinterpret_cast<const bf16x8_t*>(
                Wt + ((long)(s >> 3)) * DMODEL + k0 + (s & 7) * 8);
        }
        bf16x8_t xv;
        xv[0] = (bf16_t)xa.x; xv[1] = (bf16_t)xa.y;
        xv[2] = (bf16_t)xa.z; xv[3] = (bf16_t)xa.w;
        xv[4] = (bf16_t)xb.x; xv[5] = (bf16_t)xb.y;
        xv[6] = (bf16_t)xb.z; xv[7] = (bf16_t)xb.w;

        __syncthreads();
        *reinterpret_cast<bf16x8_t*>(
            (char*)xs + srow * 128 + ((sseg ^ (srow & 7)) * 16)) = xv;
#pragma unroll
        for (int i = 0; i < 3; ++i) {
            const int s = tid + i * 512;
            const int wrow = s >> 3, wseg = s & 7;
            *reinterpret_cast<bf16x8_t*>(
                (char*)ws + wrow * 128 + ((wseg ^ (wrow & 7)) * 16)) = wreg[i];
        }
        __syncthreads();

#pragma unroll
        for (int ks = 0; ks < 2; ++ks) {
            const int sb = ks * 4;
            bf16x8_t afr[2], bfr[3];
#pragma unroll
            for (int mt = 0; mt < 2; ++mt) {
                const int row = mrow + mt * 16 + n;
                afr[mt] = *reinterpret_cast<const bf16x8_t*>(
                    (char*)xs + row * 128 + (((sb + g) ^ (row & 7)) * 16));
            }
#pragma unroll
            for (int nt = 0; nt < 3; ++nt) {
                const int row = ncol + nt * 16 + n;
                bfr[nt] = *reinterpret_cast<const bf16x8_t*>(
                    (char*)ws + row * 128 + (((sb + g) ^ (row & 7)) * 16));
            }
#pragma unroll
            for (int mt = 0; mt < 2; ++mt)
#pragma unroll
                for (int nt = 0; nt < 3; ++nt)
                    acc[mt][nt] = __builtin_amdgcn_mfma_f32_16x16x32_bf16(
                        afr[mt], bfr[nt], acc[mt][nt], 0, 0, 0);
        }
    }

#pragma unroll
    for (int nt = 0; nt < 3; ++nt) {
        const int c = ncol + nt * 16 + n;
        float bias;
        if (c < 64)       bias = bq[c];
        else if (c < 128) bias = bk[c - 64];
        else              bias = bv[c - 128];
#pragma unroll
        for (int mt = 0; mt < 2; ++mt) {
#pragma unroll
            for (int r = 0; r < 4; ++r) {
                const int row = mrow + mt * 16 + 4 * g + r;
                const float val = acc[mt][nt][r] + bias;
                if (c < 64)
                    Qb[(rowbase + row) * HDIM + c] = (bf16_t)(val * QSCALE);
                else if (c < 128)
                    Kb[(rowbase + row) * HDIM + (c - 64)] = (bf16_t)val;
                else
                    vs[c - 128][row] = (bf16_t)val;
            }
        }
    }
    __syncthreads();
    {
        const int h = tid >> 3, sj = (tid & 7) * 8;
        const int bb = (int)(rowbase >> 12);
        const int s0 = (int)(rowbase & (S_LEN - 1));
        const bf16x8_t vv = *reinterpret_cast<const bf16x8_t*>(&vs[h][sj]);
        *reinterpret_cast<bf16x8_t*>(
            Vt + ((long)(bb * 64 + h)) * S_LEN + s0 + sj) = vv;
    }
}

// ---------------------------------------------------------------------------
// Kernel 2: causal flash attention, split-K x8, swapped QK^T, balanced pairs.
// 512-thr blocks (8 waves); wave w takes key-blocks j = w mod 8 of the pair
// (p, NQT-1-p).  Grid 512 blocks -> 16 waves/CU (4/SIMD): TLP hides L2
// latency.  Single-buffered K regs at iter start; V issued after QK^T
// (latency hidden under softmax).  exp2 domain (Q pre-scaled by log2e/8).
// ---------------------------------------------------------------------------
__global__ __launch_bounds__(512, 4) void attn_kernel(
    const bf16_t* __restrict__ Qb, const bf16_t* __restrict__ Kb,
    const bf16_t* __restrict__ Vt, float* __restrict__ out)
{
    __shared__ bf16_t plds[8][16 * 64];   // per-wave swizzled P, 16 KB
    __shared__ float  olds[8][16][64];    // 32 KB
    __shared__ float  mlds[8][16];
    __shared__ float  llds[8][16];

    const int tid  = threadIdx.x;
    const int w    = tid >> 6;            // 0..7
    const int lane = tid & 63;
    const int g    = lane >> 4, n = lane & 15;
    const int b    = blockIdx.y;
    const long bS  = (long)b * S_LEN;
    const long bV  = (long)b * 64;
    const int  swz = (n & 7) << 4;
    const f32x4_t zero = {0.f, 0.f, 0.f, 0.f};
    char* const pb = (char*)plds[w];

#pragma unroll 1
    for (int half = 0; half < 2; ++half) {
        const int tile = half ? (NQT - 1 - blockIdx.x) : blockIdx.x;
        const int q0   = tile * 16;
        const int nkb  = (q0 >> 6) + 1;   // 64-key blocks (causal)

        const bf16_t* qbase = &Qb[(bS + q0 + n) * HDIM + g * 8];
        const bf16x8_t bq0 = *reinterpret_cast<const bf16x8_t*>(qbase);
        const bf16x8_t bq1 = *reinterpret_cast<const bf16x8_t*>(qbase + 32);

        f32x4_t o[4];
#pragma unroll
        for (int nt = 0; nt < 4; ++nt) o[nt] = zero;
        float m_run = -1e30f;   // running max (log2 domain) for q = q0+n
        float l_par = 0.f;

#pragma unroll 1
        for (int j = w; j < nkb; j += 8) {
            const int k0 = j * 64;

            // ---- K tile -> regs (single buffer; TLP hides the latency)
            const bf16_t* kb = &Kb[(bS + k0 + n) * HDIM + g * 8];
            bf16x8_t kr[8];
#pragma unroll
            for (int f = 0; f < 4; ++f) {
                kr[2 * f]     = *reinterpret_cast<const bf16x8_t*>(kb + f * 16 * HDIM);
                kr[2 * f + 1] = *reinterpret_cast<const bf16x8_t*>(kb + f * 16 * HDIM + 32);
            }

            // ---- QK^T (swapped): lane (g,n) -> S[key=k0+16f+4g+r][q=q0+n]
            f32x4_t s[4];
            __builtin_amdgcn_s_setprio(1);
#pragma unroll
            for (int f = 0; f < 4; ++f) {
                s[f] = __builtin_amdgcn_mfma_f32_16x16x32_bf16(kr[2 * f],     bq0, zero, 0, 0, 0);
                s[f] = __builtin_amdgcn_mfma_f32_16x16x32_bf16(kr[2 * f + 1], bq1, s[f], 0, 0, 0);
            }
            __builtin_amdgcn_s_setprio(0);

            // ---- V tile -> regs (issued now; latency hidden under softmax)
            const bf16_t* vb = &Vt[(bV + n) * S_LEN + k0 + g * 8];
            bf16x8_t vr[8];
#pragma unroll
            for (int ks = 0; ks < 2; ++ks)
#pragma unroll
                for (int nt = 0; nt < 4; ++nt)
                    vr[ks * 4 + nt] = *reinterpret_cast<const bf16x8_t*>(
                        vb + (long)(nt * 16) * S_LEN + ks * 32);

            if (j == nkb - 1) {   // diagonal block only
                const int q = q0 + n;
#pragma unroll
                for (int f = 0; f < 4; ++f)
#pragma unroll
                    for (int r = 0; r < 4; ++r)
                        if (k0 + 16 * f + 4 * g + r > q) s[f][r] = -1e30f;
            }

            // ---- column max: 15 local + 2 shfl
            float fm0 = fmaxf(fmaxf(s[0][0], s[0][1]), fmaxf(s[0][2], s[0][3]));
            float fm1 = fmaxf(fmaxf(s[1][0], s[1][1]), fmaxf(s[1][2], s[1][3]));
            float fm2 = fmaxf(fmaxf(s[2][0], s[2][1]), fmaxf(s[2][2], s[2][3]));
            float fm3 = fmaxf(fmaxf(s[3][0], s[3][1]), fmaxf(s[3][2], s[3][3]));
            float pm = fmaxf(fmaxf(fm0, fm1), fmaxf(fm2, fm3));
            pm = fmaxf(pm, __shfl_xor(pm, 16));
            pm = fmaxf(pm, __shfl_xor(pm, 32));

            if (__any(pm > m_run + DTHR)) {   // T13 defer-max
                const float mn = fmaxf(m_run, pm);
                const float al = ex2(m_run - mn);
                m_run = mn;
                l_par *= al;
#pragma unroll
                for (int r = 0; r < 4; ++r) {
                    const float ar = __shfl(al, 4 * g + r);
#pragma unroll
                    for (int nt = 0; nt < 4; ++nt) o[nt][r] *= ar;
                }
            }

            // ---- P = exp2(s - m) -> swizzled per-wave LDS
#pragma unroll
            for (int f = 0; f < 4; ++f) {
                bf16x4_t pk;
#pragma unroll
                for (int r = 0; r < 4; ++r) {
                    const float p = ex2(s[f][r] - m_run);
                    l_par += p;
                    pk[r] = (bf16_t)p;
                }
                *reinterpret_cast<bf16x4_t*>(pb + n * 128 + ((32 * f + 8 * g) ^ swz)) = pk;
            }

            // ---- PV (same-wave DS in-order: no fence needed)
            __builtin_amdgcn_s_setprio(1);
#pragma unroll
            for (int ks = 0; ks < 2; ++ks) {
                const bf16x8_t pa = *reinterpret_cast<const bf16x8_t*>(
                    pb + n * 128 + ((64 * ks + 16 * g) ^ swz));
#pragma unroll
                for (int nt = 0; nt < 4; ++nt)
                    o[nt] = __builtin_amdgcn_mfma_f32_16x16x32_bf16(
                        pa, vr[ks * 4 + nt], o[nt], 0, 0, 0);
            }
            __builtin_amdgcn_s_setprio(0);
        }

        // ---- finish l across g-lanes
        float l_run = l_par;
        l_run += __shfl_xor(l_run, 16);
        l_run += __shfl_xor(l_run, 32);

        // ---- publish per-wave partials
        if (g == 0) { mlds[w][n] = m_run; llds[w][n] = l_run; }
#pragma unroll
        for (int nt = 0; nt < 4; ++nt)
#pragma unroll
            for (int r = 0; r < 4; ++r)
                olds[w][4 * g + r][nt * 16 + n] = o[nt][r];
        __syncthreads();

        // ---- merge 8 split-K partials, write fp32 out
        {
            const int c  = tid & 63;
            const int rg = tid >> 6;
#pragma unroll
            for (int i = 0; i < 2; ++i) {
                const int row = rg * 2 + i;
                float mm = mlds[0][row];
#pragma unroll
                for (int u = 1; u < 8; ++u) mm = fmaxf(mm, mlds[u][row]);
                float den = 0.f, num = 0.f;
#pragma unroll
                for (int u = 0; u < 8; ++u) {
                    const float a = ex2(mlds[u][row] - mm);
                    den += llds[u][row] * a;
                    num += olds[u][row][c] * a;
                }
                out[(bS + q0 + row) * HDIM + c] = num / den;
            }
        }
        __syncthreads();   // LDS reused by second half
    }
}

// ---------------------------------------------------------------------------
extern "C" void kernel_launch(void* const* d_in, const int* in_sizes, int n_in,
                              void* d_out, int out_size, void* d_ws, size_t ws_size,
                              hipStream_t stream)
{
    const float* x  = (const float*)d_in[0];
    const float* Wk = (const float*)d_in[1];
    const float* bk = (const float*)d_in[2];
    const float* Wq = (const float*)d_in[3];
    const float* bq = (const float*)d_in[4];
    const float* Wv = (const float*)d_in[5];
    const float* bv = (const float*)d_in[6];
    float* out = (float*)d_out;

    const size_t elems = (size_t)BATCH * S_LEN * HDIM;  // 1,048,576
    bf16_t* Qb = (bf16_t*)d_ws;
    bf16_t* Kb = Qb + elems;
    bf16_t* Vt = Kb + elems;
    bf16_t* Wt = Vt + elems;   // 192*1024 bf16

    wt_kernel<<<dim3(DMODEL / 64, 3), 256, 0, stream>>>(Wk, Wq, Wv, Wt);
    qkv_mfma_kernel<<<256, 512, 0, stream>>>(x, Wt, bk, bq, bv, Qb, Kb, Vt);
    attn_kernel<<<dim3(NQT / 2, BATCH), 512, 0, stream>>>(Qb, Kb, Vt, out);
}